// Round 1
// baseline (1300.468 us; speedup 1.0000x reference)
//
#include <hip/hip_runtime.h>

#define V1     32001
#define EMBD   100
#define UNITS  1000
#define BATCH  64
#define SEQ    25
#define NROWS  (BATCH * SEQ)   // 1600

#define A_UTILE   40
#define A_UBLOCKS 25           // 25 * 40 = 1000 rows of M
#define A_KSPLIT  16
#define A_CHUNK   ((V1 + A_KSPLIT - 1) / A_KSPLIT)   // 2001

// ---------------------------------------------------------------------------
// Kernel A: M[u][e] = sum_v fc_w[u][v] * emb[v][e]   (split-K, atomicAdd)
// Block: 256 threads = (e-lane 0..127, uh 0..1); each thread owns 20 u-rows.
// ---------------------------------------------------------------------------
__global__ __launch_bounds__(256) void kernelA(
    const float* __restrict__ fcw, const float* __restrict__ emb,
    float* __restrict__ M)
{
    const int tid    = threadIdx.x;
    const int e      = tid & 127;
    const int uh     = tid >> 7;
    const int ec     = (e < EMBD) ? e : 0;     // clamp idle lanes
    const int ublock = blockIdx.x % A_UBLOCKS;
    const int kchunk = blockIdx.x / A_UBLOCKS;
    const int u0     = ublock * A_UTILE + uh * 20;
    const int v0     = kchunk * A_CHUNK;
    const int v1     = min(v0 + A_CHUNK, V1);

    float acc[20];
#pragma unroll
    for (int j = 0; j < 20; ++j) acc[j] = 0.f;

    const float* wbase = fcw + u0 * V1;

    int v = v0;
    for (; v + 4 <= v1; v += 4) {
        const float e0 = emb[(v + 0) * EMBD + ec];
        const float e1 = emb[(v + 1) * EMBD + ec];
        const float e2 = emb[(v + 2) * EMBD + ec];
        const float e3 = emb[(v + 3) * EMBD + ec];
#pragma unroll
        for (int j = 0; j < 20; ++j) {
            const float* wp = wbase + j * V1 + v;
            const float w0 = wp[0], w1 = wp[1], w2 = wp[2], w3 = wp[3];
            acc[j] += w0 * e0;
            acc[j] += w1 * e1;
            acc[j] += w2 * e2;
            acc[j] += w3 * e3;
        }
    }
    for (; v < v1; ++v) {
        const float ev = emb[v * EMBD + ec];
#pragma unroll
        for (int j = 0; j < 20; ++j)
            acc[j] += wbase[j * V1 + v] * ev;
    }

    if (e < EMBD) {
#pragma unroll
        for (int j = 0; j < 20; ++j)
            atomicAdd(&M[(u0 + j) * EMBD + e], acc[j]);
    }
}

// ---------------------------------------------------------------------------
// Kernel V: v[e] = sum_j fc_b[j] * emb[j][e]   (fc_b is zeros in setup, but
// computed faithfully; tiny)
// ---------------------------------------------------------------------------
__global__ __launch_bounds__(128) void kernelV(
    const float* __restrict__ fcb, const float* __restrict__ emb,
    float* __restrict__ vout)
{
    const int e  = threadIdx.x;
    const int ec = (e < EMBD) ? e : 0;
    const int chunk = (V1 + gridDim.x - 1) / gridDim.x;
    const int j0 = blockIdx.x * chunk;
    const int j1 = min(j0 + chunk, V1);
    float acc = 0.f;
    for (int j = j0; j < j1; ++j)
        acc += fcb[j] * emb[j * EMBD + ec];
    if (e < EMBD) atomicAdd(&vout[e], acc);
}

// ---------------------------------------------------------------------------
// Kernel BC (fused decoder + projection):
//   token -> emb lookup -> GRU gates with h=0 -> h1 (kept in LDS)
//   out[i][e] = v[e] + sum_u h1[i][u] * M[u][e]
// Block handles 8 rows of the 1600.
// ---------------------------------------------------------------------------
__global__ __launch_bounds__(256) void kernelBC(
    const int* __restrict__ target, const int* __restrict__ start_tok,
    const float* __restrict__ emb, const float* __restrict__ K,
    const float* __restrict__ bias, const float* __restrict__ M,
    const float* __restrict__ vvec, float* __restrict__ out)
{
    __shared__ float xs[8][EMBD];
    __shared__ float h1s[8][UNITS];
    __shared__ int   msk[8];

    const int tid   = threadIdx.x;
    const int ibase = blockIdx.x * 8;

    {   // stage embeddings for 8 rows; r = tid/32 covers 0..7
        const int r = tid >> 5, c = tid & 31;
        const int i = ibase + r;
        const int b = i / SEQ, t = i % SEQ;
        const int token = (t == 0) ? start_tok[0] : target[b * SEQ + t - 1];
        if (c == 0) msk[r] = (token != 0);
        for (int cc = c; cc < EMBD; cc += 32)
            xs[r][cc] = emb[token * EMBD + cc];
    }
    __syncthreads();

    const float* b0 = bias;
    const float* b1 = bias + 3 * UNITS;

    for (int ui = 0; ui < 4; ++ui) {
        const int u  = ui * 256 + tid;
        const int uc = (u < UNITS) ? u : 0;
        float az[8], ar[8], ah[8];
#pragma unroll
        for (int r = 0; r < 8; ++r) { az[r] = 0.f; ar[r] = 0.f; ah[r] = 0.f; }
        for (int k = 0; k < EMBD; ++k) {
            const float wz = K[k * 3 * UNITS + uc];
            const float wr = K[k * 3 * UNITS + UNITS + uc];
            const float wh = K[k * 3 * UNITS + 2 * UNITS + uc];
#pragma unroll
            for (int r = 0; r < 8; ++r) {
                const float x = xs[r][k];
                az[r] += x * wz;
                ar[r] += x * wr;
                ah[r] += x * wh;
            }
        }
        if (u < UNITS) {
            const float bz  = b0[u] + b1[u];
            const float br  = b0[UNITS + u] + b1[UNITS + u];
            const float bh0 = b0[2 * UNITS + u];
            const float bh1 = b1[2 * UNITS + u];
#pragma unroll
            for (int r = 0; r < 8; ++r) {
                const float z   = 1.f / (1.f + __expf(-(az[r] + bz)));
                const float rg  = 1.f / (1.f + __expf(-(ar[r] + br)));
                const float pre = ah[r] + bh0 + rg * bh1;
                const float ex  = __expf(2.f * pre);      // tanh via exp
                const float hh  = 1.f - 2.f / (ex + 1.f);
                h1s[r][u] = msk[r] ? (1.f - z) * hh : 0.f;
            }
        }
    }
    __syncthreads();

    // phase 2: project through M (h1 stays in LDS; M coalesced from L2)
    const int e  = tid & 127;
    const int g  = tid >> 7;
    const int ec = (e < EMBD) ? e : 0;
    float acc0 = 0.f, acc1 = 0.f, acc2 = 0.f, acc3 = 0.f;
    for (int u = 0; u < UNITS; ++u) {
        const float m = M[u * EMBD + ec];
        acc0 += h1s[g * 4 + 0][u] * m;
        acc1 += h1s[g * 4 + 1][u] * m;
        acc2 += h1s[g * 4 + 2][u] * m;
        acc3 += h1s[g * 4 + 3][u] * m;
    }
    if (e < EMBD) {
        const float ve = vvec[e];
        out[(ibase + g * 4 + 0) * EMBD + e] = acc0 + ve;
        out[(ibase + g * 4 + 1) * EMBD + e] = acc1 + ve;
        out[(ibase + g * 4 + 2) * EMBD + e] = acc2 + ve;
        out[(ibase + g * 4 + 3) * EMBD + e] = acc3 + ve;
    }
}

// ---------------------------------------------------------------------------
extern "C" void kernel_launch(void* const* d_in, const int* in_sizes, int n_in,
                              void* d_out, int out_size, void* d_ws, size_t ws_size,
                              hipStream_t stream)
{
    // setup_inputs order:
    // 0:x 1:target 2:start_token 3:emb_table 4:enc_kernel 5:enc_recurrent
    // 6:enc_bias 7:dec_kernel 8:dec_recurrent 9:dec_bias 10:fc_w 11:fc_b
    const int*   target     = (const int*)d_in[1];
    const int*   start_tok  = (const int*)d_in[2];
    const float* emb        = (const float*)d_in[3];
    const float* dec_kernel = (const float*)d_in[7];
    const float* dec_bias   = (const float*)d_in[9];
    const float* fc_w       = (const float*)d_in[10];
    const float* fc_b       = (const float*)d_in[11];

    float* M    = (float*)d_ws;             // 1000*100 floats
    float* vvec = M + UNITS * EMBD;         // 100 floats (padded to 128)
    float* out  = (float*)d_out;

    // ws is poisoned 0xAA before every call -> zero the accumulator regions
    hipMemsetAsync(d_ws, 0, (UNITS * EMBD + 128) * sizeof(float), stream);

    kernelA<<<A_UBLOCKS * A_KSPLIT, 256, 0, stream>>>(fc_w, emb, M);
    kernelV<<<25, 128, 0, stream>>>(fc_b, emb, vvec);
    kernelBC<<<NROWS / 8, 256, 0, stream>>>(target, start_tok, emb, dec_kernel,
                                            dec_bias, M, vvec, out);
}

// Round 2
// 415.139 us; speedup vs baseline: 3.1326x; 3.1326x over previous
//
#include <hip/hip_runtime.h>

typedef __bf16 bf16;
typedef __bf16 bf16x8 __attribute__((ext_vector_type(8)));
typedef float  floatx4 __attribute__((ext_vector_type(4)));

#define V1     32001
#define EMBD   100
#define UNITS  1000
#define SEQ    25
#define NROWS  1600
#define KPAD   32032          // ET padded K (bf16), k>=32000 zeroed
#define KSPLIT 32             // k-units of 32 per block chunk

// ---------------------------------------------------------------------------
// kT: transpose+convert  E[32001][100] fp32  ->  ET[100][KPAD] bf16
//     k >= 32000 zeroed (k=32000 handled by rank-1 fixup kD)
// ---------------------------------------------------------------------------
__global__ __launch_bounds__(256) void kT(const float* __restrict__ E,
                                          bf16* __restrict__ ET)
{
    __shared__ bf16 lds[100 * 66];      // pad 64 -> 66 halfs: conflict-free
    const int tid = threadIdx.x;
    const int k0  = blockIdx.x * 64;
    const int e   = tid & 127;
    const int kh  = tid >> 7;
    for (int kk = kh; kk < 64; kk += 2) {
        const int k = k0 + kk;
        float v = 0.f;
        if (k < 32000 && e < 100) v = E[k * 100 + e];
        if (e < 100) lds[e * 66 + kk] = (bf16)v;
    }
    __syncthreads();
    const int kl = tid & 63;
    const int eh = tid >> 6;
    if (k0 + kl < KPAD) {
        for (int ee = eh; ee < 100; ee += 4)
            ET[ee * KPAD + k0 + kl] = lds[ee * 66 + kl];
    }
}

// ---------------------------------------------------------------------------
// kA: M[1000][100] += W[1000][32001] @ E  via bf16 MFMA 16x16x32.
// Block = 4 waves; wave = 16m strip x 7 n-tiles (112 >= 100), no LDS.
// Grid = 16 m-blocks x KSPLIT k-blocks. atomicAdd fp32 reduction.
// ---------------------------------------------------------------------------
__global__ __launch_bounds__(256) void kA(const float* __restrict__ W,
                                          const bf16* __restrict__ ET,
                                          float* __restrict__ M)
{
    const int tid   = threadIdx.x;
    const int lane  = tid & 63;
    const int wv    = tid >> 6;
    const int mb    = blockIdx.x & 15;
    const int kb    = blockIdx.x >> 4;
    const int row16 = lane & 15;
    const int quad  = lane >> 4;

    const int m  = mb * 64 + wv * 16 + row16;
    const int mc = min(m, UNITS - 1);
    const int u0   = kb * KSPLIT;                    // first 32-wide k-unit
    const int uend = min(KSPLIT, 1000 - u0);         // 1000 units total

    floatx4 acc[7];
#pragma unroll
    for (int t = 0; t < 7; ++t) acc[t] = (floatx4){0.f, 0.f, 0.f, 0.f};

    const float* wrow = W + (long)mc * V1;

    for (int un = 0; un < uend; ++un) {
        const int k0 = (u0 + un) * 32 + quad * 8;
        bf16x8 a;
        {
            float f[8];
            __builtin_memcpy(f, wrow + k0, 32);      // align-safe (4B rows)
#pragma unroll
            for (int j = 0; j < 8; ++j) a[j] = (bf16)f[j];
        }
#pragma unroll
        for (int t = 0; t < 7; ++t) {
            const int nc = min(t * 16 + row16, 99);
            const bf16x8 b = *(const bf16x8*)(ET + (long)nc * KPAD + k0);
            acc[t] = __builtin_amdgcn_mfma_f32_16x16x32_bf16(a, b, acc[t], 0, 0, 0);
        }
    }

    const int orow0 = mb * 64 + wv * 16 + quad * 4;  // C/D: row=(lane>>4)*4+r
#pragma unroll
    for (int t = 0; t < 7; ++t) {
        const int col = t * 16 + row16;              // C/D: col=lane&15
        if (col < 100) {
#pragma unroll
            for (int r = 0; r < 4; ++r) {
                const int orow = orow0 + r;
                if (orow < UNITS)
                    atomicAdd(&M[orow * 100 + col], acc[t][r]);
            }
        }
    }
}

// ---------------------------------------------------------------------------
// kD: rank-1 fixup for the K tail: M[u][e] += W[u][32000] * E[32000][e]
// ---------------------------------------------------------------------------
__global__ __launch_bounds__(256) void kD(const float* __restrict__ W,
                                          const float* __restrict__ E,
                                          float* __restrict__ M)
{
    const int idx = blockIdx.x * 256 + threadIdx.x;
    if (idx >= UNITS * 100) return;
    const int u = idx / 100;
    const int e = idx - u * 100;
    M[idx] += W[(long)u * V1 + 32000] * E[32000 * 100 + e];
}

// ---------------------------------------------------------------------------
// kV: v[e] = sum_j fc_b[j] * emb[j][e]    (256 blocks for parallelism)
// ---------------------------------------------------------------------------
__global__ __launch_bounds__(256) void kV(const float* __restrict__ fcb,
                                          const float* __restrict__ emb,
                                          float* __restrict__ vout)
{
    const int tid = threadIdx.x;
    const int e   = tid & 127;
    const int g   = tid >> 7;
    const int ec  = min(e, 99);
    const int slice = blockIdx.x * 2 + g;            // 512 slices
    const int chunk = (V1 + 511) / 512;              // 63
    const int j0 = slice * chunk;
    const int j1 = min(j0 + chunk, V1);
    float acc = 0.f;
    for (int j = j0; j < j1; ++j)
        acc += fcb[j] * emb[j * 100 + ec];
    if (e < 100) atomicAdd(&vout[e], acc);
}

// ---------------------------------------------------------------------------
// kB: decoder gates (h=0 GRU step) -> h1[1600][1000] fp32 in ws.
// Grid = 4 u-chunks x 200 row-groups = 800 blocks.
// ---------------------------------------------------------------------------
__global__ __launch_bounds__(256) void kB(const int* __restrict__ target,
                                          const int* __restrict__ stok,
                                          const float* __restrict__ emb,
                                          const float* __restrict__ K,
                                          const float* __restrict__ bias,
                                          float* __restrict__ h1)
{
    __shared__ float xs[8][100];
    __shared__ int   msk[8];
    const int tid   = threadIdx.x;
    const int rg    = blockIdx.x % 200;
    const int uc    = blockIdx.x / 200;
    const int ibase = rg * 8;

    {
        const int r = tid >> 5, c = tid & 31;
        const int i = ibase + r;
        const int b = i / SEQ, t = i - b * SEQ;
        const int token = (t == 0) ? stok[0] : target[b * SEQ + t - 1];
        if (c == 0) msk[r] = (token != 0);
        for (int cc = c; cc < 100; cc += 32)
            xs[r][cc] = emb[token * 100 + cc];
    }
    __syncthreads();

    const int u   = uc * 256 + tid;
    const int ucl = min(u, UNITS - 1);
    float az[8], ar[8], ah[8];
#pragma unroll
    for (int r = 0; r < 8; ++r) { az[r] = 0.f; ar[r] = 0.f; ah[r] = 0.f; }

#pragma unroll 2
    for (int k = 0; k < 100; ++k) {
        const float wz = K[k * 3000 + ucl];
        const float wr = K[k * 3000 + 1000 + ucl];
        const float wh = K[k * 3000 + 2000 + ucl];
#pragma unroll
        for (int r = 0; r < 8; ++r) {
            const float x = xs[r][k];
            az[r] += x * wz;
            ar[r] += x * wr;
            ah[r] += x * wh;
        }
    }

    if (u < UNITS) {
        const float* b0 = bias;
        const float* b1 = bias + 3000;
        const float bz  = b0[u] + b1[u];
        const float br  = b0[1000 + u] + b1[1000 + u];
        const float bh0 = b0[2000 + u];
        const float bh1 = b1[2000 + u];
#pragma unroll
        for (int r = 0; r < 8; ++r) {
            const float z   = 1.f / (1.f + __expf(-(az[r] + bz)));
            const float rg_ = 1.f / (1.f + __expf(-(ar[r] + br)));
            const float pre = ah[r] + bh0 + rg_ * bh1;
            const float ex  = __expf(2.f * pre);
            const float hh  = 1.f - 2.f / (ex + 1.f);
            h1[(ibase + r) * UNITS + u] = msk[r] ? (1.f - z) * hh : 0.f;
        }
    }
}

// ---------------------------------------------------------------------------
// kC: out[1600][100] = h1 @ M + v.  Grid 400 blocks x 4 rows.
// ---------------------------------------------------------------------------
__global__ __launch_bounds__(256) void kC(const float* __restrict__ h1,
                                          const float* __restrict__ M,
                                          const float* __restrict__ v,
                                          float* __restrict__ out)
{
    __shared__ float hs[4 * UNITS];
    const int tid = threadIdx.x;
    const int r0  = blockIdx.x * 4;
    for (int i = tid; i < 4 * UNITS; i += 256)
        hs[i] = h1[r0 * UNITS + i];
    __syncthreads();

    const int e  = tid & 127;
    const int rp = tid >> 7;            // wave-uniform
    const int ec = min(e, 99);
    float a0 = 0.f, a1 = 0.f;
#pragma unroll 4
    for (int u = 0; u < UNITS; ++u) {
        const float m = M[u * 100 + ec];
        a0 += hs[(rp * 2 + 0) * UNITS + u] * m;
        a1 += hs[(rp * 2 + 1) * UNITS + u] * m;
    }
    if (e < 100) {
        const float ve = v[ec];
        out[(r0 + rp * 2 + 0) * 100 + e] = a0 + ve;
        out[(r0 + rp * 2 + 1) * 100 + e] = a1 + ve;
    }
}

// ---------------------------------------------------------------------------
extern "C" void kernel_launch(void* const* d_in, const int* in_sizes, int n_in,
                              void* d_out, int out_size, void* d_ws, size_t ws_size,
                              hipStream_t stream)
{
    const int*   target     = (const int*)d_in[1];
    const int*   start_tok  = (const int*)d_in[2];
    const float* emb        = (const float*)d_in[3];
    const float* dec_kernel = (const float*)d_in[7];
    const float* dec_bias   = (const float*)d_in[9];
    const float* fc_w       = (const float*)d_in[10];
    const float* fc_b       = (const float*)d_in[11];

    float* M    = (float*)d_ws;                       // 100000 f32
    float* vvec = M + 100352;                         // 128 f32 (padded)
    bf16*  ET   = (bf16*)(vvec + 128);                // 100*KPAD bf16 (6.4 MB)
    float* h1   = (float*)((char*)ET + (size_t)100 * KPAD * sizeof(bf16));
    float* out  = (float*)d_out;

    hipMemsetAsync(d_ws, 0, (100352 + 128) * sizeof(float), stream);

    kT<<<(KPAD + 63) / 64, 256, 0, stream>>>(emb, ET);
    kV<<<256, 256, 0, stream>>>(fc_b, emb, vvec);
    kB<<<800, 256, 0, stream>>>(target, start_tok, emb, dec_kernel, dec_bias, h1);
    kA<<<16 * KSPLIT, 256, 0, stream>>>(fc_w, ET, M);
    kD<<<(UNITS * 100 + 255) / 256, 256, 0, stream>>>(fc_w, emb, M);
    kC<<<400, 256, 0, stream>>>(h1, M, vvec, out);
}

// Round 3
// 383.508 us; speedup vs baseline: 3.3910x; 1.0825x over previous
//
#include <hip/hip_runtime.h>

typedef _Float16 half_t;
typedef _Float16 half8 __attribute__((ext_vector_type(8)));
typedef float    floatx4 __attribute__((ext_vector_type(4)));

#define V1     32001
#define EMBD   100
#define UNITS  1000
#define SEQ    25
#define NROWS  1600
#define KPAD   32032          // ET padded K (f16), k>=32000 zeroed
#define KB_A   32             // k-blocks in kA grid
#define HSTR   1024           // h1h / MbT padded K (1000 data + 1 ones + pad)

// ---------------------------------------------------------------------------
// kT: transpose+convert  E[32001][100] fp32 -> ET[100][KPAD] f16
//     k >= 32000 zeroed (element k=32000 handled by rank-1 fixup kD)
// ---------------------------------------------------------------------------
__global__ __launch_bounds__(256) void kT(const float* __restrict__ E,
                                          half_t* __restrict__ ET)
{
    __shared__ half_t lds[100 * 66];
    const int tid = threadIdx.x;
    const int k0  = blockIdx.x * 64;
    const int e   = tid & 127;
    const int kh  = tid >> 7;
    for (int kk = kh; kk < 64; kk += 2) {
        const int k = k0 + kk;
        float v = 0.f;
        if (k < 32000 && e < 100) v = E[k * 100 + e];
        if (e < 100) lds[e * 66 + kk] = (half_t)v;
    }
    __syncthreads();
    const int kl = tid & 63;
    const int eh = tid >> 6;
    if (k0 + kl < KPAD) {
        for (int ee = eh; ee < 100; ee += 4)
            ET[(long)ee * KPAD + k0 + kl] = lds[ee * 66 + kl];
    }
}

// ---------------------------------------------------------------------------
// kA: M[1000][100] += W[1000][32001] @ E  via f16 MFMA 16x16x32.
// Grid = 63 m-blocks (16 rows) x 32 k-blocks. Block = 4 waves splitting K;
// LDS cross-wave reduce, then wave 0 atomicAdds (fp32) into M.
// ---------------------------------------------------------------------------
__global__ __launch_bounds__(256) void kA(const float* __restrict__ W,
                                          const half_t* __restrict__ ET,
                                          float* __restrict__ M)
{
    __shared__ float red[3][64][29];        // stride 29: conflict-free
    const int tid   = threadIdx.x;
    const int lane  = tid & 63;
    const int wv    = tid >> 6;
    const int mb    = blockIdx.x;           // 0..62
    const int kb    = blockIdx.y;           // 0..31
    const int row16 = lane & 15;
    const int quad  = lane >> 4;

    const int m  = mb * 16 + row16;
    const int mc = min(m, UNITS - 1);

    // k-units of 32: block covers [ub, ue), wave covers a quarter
    const int ub = kb * KB_A;
    const int ue = min(ub + KB_A, 1000);
    const int pw = (ue - ub + 3) >> 2;
    const int wb = ub + wv * pw;
    const int we = min(wb + pw, ue);

    floatx4 acc[7];
#pragma unroll
    for (int t = 0; t < 7; ++t) acc[t] = (floatx4){0.f, 0.f, 0.f, 0.f};

    const float* wrow = W + (long)mc * V1;
    const half_t* bbase[7];
#pragma unroll
    for (int t = 0; t < 7; ++t) {
        const int nc = min(t * 16 + row16, 99);
        bbase[t] = ET + (long)nc * KPAD + quad * 8;
    }

#pragma unroll 2
    for (int un = wb; un < we; ++un) {
        const int k0 = un * 32 + quad * 8;
        half8 a;
        {
            float f[8];
            __builtin_memcpy(f, wrow + k0, 32);
#pragma unroll
            for (int j = 0; j < 8; ++j) a[j] = (half_t)f[j];
        }
#pragma unroll
        for (int t = 0; t < 7; ++t) {
            const half8 b = *(const half8*)(bbase[t] + un * 32);
            acc[t] = __builtin_amdgcn_mfma_f32_16x16x32_f16(a, b, acc[t], 0, 0, 0);
        }
    }

    if (wv > 0) {
#pragma unroll
        for (int t = 0; t < 7; ++t)
#pragma unroll
            for (int r = 0; r < 4; ++r)
                red[wv - 1][lane][t * 4 + r] = acc[t][r];
    }
    __syncthreads();
    if (wv == 0) {
        const int orow0 = mb * 16 + quad * 4;   // C/D: row=(lane>>4)*4+r
#pragma unroll
        for (int t = 0; t < 7; ++t) {
            const int col = t * 16 + row16;     // C/D: col=lane&15
#pragma unroll
            for (int r = 0; r < 4; ++r) {
                const float s = acc[t][r] + red[0][lane][t * 4 + r]
                              + red[1][lane][t * 4 + r] + red[2][lane][t * 4 + r];
                const int orow = orow0 + r;
                if (col < 100 && orow < UNITS)
                    atomicAdd(&M[orow * 100 + col], s);
            }
        }
    }
}

// ---------------------------------------------------------------------------
// kD: rank-1 fixup for the K tail: M[u][e] += W[u][32000] * E[32000][e]
// ---------------------------------------------------------------------------
__global__ __launch_bounds__(256) void kD(const float* __restrict__ W,
                                          const float* __restrict__ E,
                                          float* __restrict__ M)
{
    const int idx = blockIdx.x * 256 + threadIdx.x;
    if (idx >= UNITS * 100) return;
    const int u = idx / 100;
    const int e = idx - u * 100;
    M[idx] += W[(long)u * V1 + 32000] * E[32000 * 100 + e];
}

// ---------------------------------------------------------------------------
// kV: v[e] = sum_j fc_b[j] * emb[j][e]
// ---------------------------------------------------------------------------
__global__ __launch_bounds__(256) void kV(const float* __restrict__ fcb,
                                          const float* __restrict__ emb,
                                          float* __restrict__ vout)
{
    const int tid = threadIdx.x;
    const int e   = tid & 127;
    const int g   = tid >> 7;
    const int ec  = min(e, 99);
    const int slice = blockIdx.x * 2 + g;
    const int chunk = (V1 + 511) / 512;
    const int j0 = slice * chunk;
    const int j1 = min(j0 + chunk, V1);
    float acc = 0.f;
    for (int j = j0; j < j1; ++j)
        acc += fcb[j] * emb[j * 100 + ec];
    if (e < 100) atomicAdd(&vout[e], acc);
}

// ---------------------------------------------------------------------------
// kB: decoder gates (h=0 GRU step) -> h1h[1600][HSTR] f16, with col 1000 = 1
// (ones column folds the +v bias into the kC GEMM), cols 1001..1023 = 0.
// ---------------------------------------------------------------------------
__global__ __launch_bounds__(256) void kB(const int* __restrict__ target,
                                          const int* __restrict__ stok,
                                          const float* __restrict__ emb,
                                          const float* __restrict__ K,
                                          const float* __restrict__ bias,
                                          half_t* __restrict__ h1h)
{
    __shared__ float xs[8][100];
    __shared__ int   msk[8];
    const int tid   = threadIdx.x;
    const int rg    = blockIdx.x % 200;
    const int uc    = blockIdx.x / 200;
    const int ibase = rg * 8;

    {
        const int r = tid >> 5, c = tid & 31;
        const int i = ibase + r;
        const int b = i / SEQ, t = i - b * SEQ;
        const int token = (t == 0) ? stok[0] : target[b * SEQ + t - 1];
        if (c == 0) msk[r] = (token != 0);
        for (int cc = c; cc < 100; cc += 32)
            xs[r][cc] = emb[token * 100 + cc];
    }
    __syncthreads();

    const int u = uc * 256 + tid;
    if (u < UNITS) {
        float az[8], ar[8], ah[8];
#pragma unroll
        for (int r = 0; r < 8; ++r) { az[r] = 0.f; ar[r] = 0.f; ah[r] = 0.f; }
#pragma unroll 2
        for (int k = 0; k < 100; ++k) {
            const float wz = K[k * 3000 + u];
            const float wr = K[k * 3000 + 1000 + u];
            const float wh = K[k * 3000 + 2000 + u];
#pragma unroll
            for (int r = 0; r < 8; ++r) {
                const float x = xs[r][k];
                az[r] += x * wz;
                ar[r] += x * wr;
                ah[r] += x * wh;
            }
        }
        const float* b0 = bias;
        const float* b1 = bias + 3000;
        const float bz  = b0[u] + b1[u];
        const float br  = b0[1000 + u] + b1[1000 + u];
        const float bh0 = b0[2000 + u];
        const float bh1 = b1[2000 + u];
#pragma unroll
        for (int r = 0; r < 8; ++r) {
            const float z   = 1.f / (1.f + __expf(-(az[r] + bz)));
            const float rg_ = 1.f / (1.f + __expf(-(ar[r] + br)));
            const float pre = ah[r] + bh0 + rg_ * bh1;
            const float ex  = __expf(2.f * pre);
            const float hh  = 1.f - 2.f / (ex + 1.f);
            h1h[(ibase + r) * HSTR + u] = (half_t)(msk[r] ? (1.f - z) * hh : 0.f);
        }
    } else {
        const half_t cv = (half_t)((u == 1000) ? 1.f : 0.f);
#pragma unroll
        for (int r = 0; r < 8; ++r)
            h1h[(ibase + r) * HSTR + u] = cv;
    }
}

// ---------------------------------------------------------------------------
// kM: MbT[100][HSTR] f16:  MbT[e][k<1000] = M[k][e];  [e][1000] = v[e]; else 0
// ---------------------------------------------------------------------------
__global__ __launch_bounds__(256) void kM(const float* __restrict__ M,
                                          const float* __restrict__ v,
                                          half_t* __restrict__ MbT)
{
    const int idx = blockIdx.x * 256 + threadIdx.x;
    if (idx >= 100 * HSTR) return;
    const int e = idx >> 10;
    const int k = idx & (HSTR - 1);
    const float val = (k < 1000) ? M[k * 100 + e] : ((k == 1000) ? v[e] : 0.f);
    MbT[idx] = (half_t)val;
}

// ---------------------------------------------------------------------------
// kC: out[1600][100] = [h1|1] @ [M;v]  via f16 MFMA. 1 wave / 16 rows.
// ---------------------------------------------------------------------------
__global__ __launch_bounds__(64) void kC(const half_t* __restrict__ h1h,
                                         const half_t* __restrict__ MbT,
                                         float* __restrict__ out)
{
    const int lane  = threadIdx.x;
    const int rb    = blockIdx.x;          // 0..99
    const int row16 = lane & 15;
    const int quad  = lane >> 4;

    const half_t* arow = h1h + (long)(rb * 16 + row16) * HSTR + quad * 8;
    const half_t* bbase[7];
#pragma unroll
    for (int t = 0; t < 7; ++t) {
        const int nc = min(t * 16 + row16, 99);
        bbase[t] = MbT + (long)nc * HSTR + quad * 8;
    }

    floatx4 acc[7];
#pragma unroll
    for (int t = 0; t < 7; ++t) acc[t] = (floatx4){0.f, 0.f, 0.f, 0.f};

#pragma unroll 2
    for (int un = 0; un < 32; ++un) {
        const half8 a = *(const half8*)(arow + un * 32);
#pragma unroll
        for (int t = 0; t < 7; ++t) {
            const half8 b = *(const half8*)(bbase[t] + un * 32);
            acc[t] = __builtin_amdgcn_mfma_f32_16x16x32_f16(a, b, acc[t], 0, 0, 0);
        }
    }

    const int orow0 = rb * 16 + quad * 4;
#pragma unroll
    for (int t = 0; t < 7; ++t) {
        const int col = t * 16 + row16;
        if (col < 100) {
#pragma unroll
            for (int r = 0; r < 4; ++r)
                out[(orow0 + r) * 100 + col] = acc[t][r];
        }
    }
}

// ---------------------------------------------------------------------------
extern "C" void kernel_launch(void* const* d_in, const int* in_sizes, int n_in,
                              void* d_out, int out_size, void* d_ws, size_t ws_size,
                              hipStream_t stream)
{
    const int*   target     = (const int*)d_in[1];
    const int*   start_tok  = (const int*)d_in[2];
    const float* emb        = (const float*)d_in[3];
    const float* dec_kernel = (const float*)d_in[7];
    const float* dec_bias   = (const float*)d_in[9];
    const float* fc_w       = (const float*)d_in[10];
    const float* fc_b       = (const float*)d_in[11];

    float*  M    = (float*)d_ws;                               // 100000 f32
    float*  vvec = M + 100352;                                 // 128 f32
    half_t* ET   = (half_t*)(vvec + 128);                      // 100*KPAD f16
    half_t* h1h  = ET + (size_t)100 * KPAD;                    // 1600*HSTR f16
    half_t* MbT  = h1h + (size_t)NROWS * HSTR;                 // 100*HSTR f16
    float*  out  = (float*)d_out;

    hipMemsetAsync(d_ws, 0, (100352 + 128) * sizeof(float), stream);

    kT<<<(KPAD + 63) / 64, 256, 0, stream>>>(emb, ET);
    kV<<<256, 256, 0, stream>>>(fc_b, emb, vvec);
    kB<<<800, 256, 0, stream>>>(target, start_tok, emb, dec_kernel, dec_bias, h1h);
    kA<<<dim3(63, KB_A), 256, 0, stream>>>(fc_w, ET, M);
    kD<<<(UNITS * 100 + 255) / 256, 256, 0, stream>>>(fc_w, emb, M);
    kM<<<(100 * HSTR + 255) / 256, 256, 0, stream>>>(M, vvec, MbT);
    kC<<<100, 64, 0, stream>>>(h1h, MbT, out);
}

// Round 4
// 318.620 us; speedup vs baseline: 4.0816x; 1.2037x over previous
//
#include <hip/hip_runtime.h>

typedef _Float16 half_t;
typedef _Float16 half8 __attribute__((ext_vector_type(8)));
typedef float    floatx4 __attribute__((ext_vector_type(4)));

#define V1     32001
#define EMBD   100
#define UNITS  1000
#define SEQ    25
#define NROWS  1600
#define KPAD   32032          // ET padded K (f16), k>=32000 zeroed
#define HSTR   1024           // h1h / MbT padded K (1000 data + ones col + pad)
#define NKB    32             // k-split blocks in kA
#define PROWS  1024           // P slab rows (>= UNITS, m-tile padded)

// ===========================================================================
// kPre: fused independent producers, dispatched by blockIdx range:
//   [0,501)      kT : E[32001][100] f32 -> ET[100][KPAD] f16 (k>=32000 zeroed)
//   [501,757)    kV : vvec[e] = sum_j fc_b[j]*emb[j][e]  (atomic, 512 slices)
//   [757,1557)   kB : GRU gates (h=0) -> h1h[1600][HSTR] f16 (+ones col 1000)
// ===========================================================================
__global__ __launch_bounds__(256) void kPre(
    const float* __restrict__ E, half_t* __restrict__ ET,
    const float* __restrict__ fcb, float* __restrict__ vvec,
    const int* __restrict__ target, const int* __restrict__ stok,
    const float* __restrict__ K, const float* __restrict__ bias,
    half_t* __restrict__ h1h)
{
    __shared__ char smem[100 * 66 * sizeof(half_t)];
    const int tid = threadIdx.x;
    const int bid = blockIdx.x;

    if (bid < 501) {                       // ---- kT ----
        half_t* lds = (half_t*)smem;
        const int k0 = bid * 64;
        const int e  = tid & 127;
        const int kh = tid >> 7;
        for (int kk = kh; kk < 64; kk += 2) {
            const int k = k0 + kk;
            float v = 0.f;
            if (k < 32000 && e < 100) v = E[k * 100 + e];
            if (e < 100) lds[e * 66 + kk] = (half_t)v;
        }
        __syncthreads();
        const int kl = tid & 63;
        const int eh = tid >> 6;
        if (k0 + kl < KPAD) {
            for (int ee = eh; ee < 100; ee += 4)
                ET[(long)ee * KPAD + k0 + kl] = lds[ee * 66 + kl];
        }
        return;
    }

    if (bid < 757) {                       // ---- kV ----
        const int e  = tid & 127;
        const int g  = tid >> 7;
        const int ec = min(e, 99);
        const int slice = (bid - 501) * 2 + g;
        const int chunk = (V1 + 511) / 512;
        const int j0 = slice * chunk;
        const int j1 = min(j0 + chunk, V1);
        float acc = 0.f;
        for (int j = j0; j < j1; ++j)
            acc += fcb[j] * E[j * 100 + ec];
        if (e < 100) atomicAdd(&vvec[e], acc);
        return;
    }

    // ---- kB ----
    float (*xs)[100] = (float(*)[100])smem;
    __shared__ int msk[8];
    const int b3    = bid - 757;
    const int rg    = b3 % 200;
    const int uc    = b3 / 200;
    const int ibase = rg * 8;
    {
        const int r = tid >> 5, c = tid & 31;
        const int i = ibase + r;
        const int bb = i / SEQ, t = i - bb * SEQ;
        const int token = (t == 0) ? stok[0] : target[bb * SEQ + t - 1];
        if (c == 0) msk[r] = (token != 0);
        for (int cc = c; cc < 100; cc += 32)
            xs[r][cc] = E[token * 100 + cc];
    }
    __syncthreads();

    const int u = uc * 256 + tid;
    if (u < UNITS) {
        float az[8], ar[8], ah[8];
#pragma unroll
        for (int r = 0; r < 8; ++r) { az[r] = 0.f; ar[r] = 0.f; ah[r] = 0.f; }
#pragma unroll 4
        for (int k = 0; k < 100; ++k) {
            const float wz = K[k * 3000 + u];
            const float wr = K[k * 3000 + 1000 + u];
            const float wh = K[k * 3000 + 2000 + u];
#pragma unroll
            for (int r = 0; r < 8; ++r) {
                const float x = xs[r][k];
                az[r] += x * wz;
                ar[r] += x * wr;
                ah[r] += x * wh;
            }
        }
        const float* b0 = bias;
        const float* b1 = bias + 3000;
        const float bz  = b0[u] + b1[u];
        const float br  = b0[1000 + u] + b1[1000 + u];
        const float bh0 = b0[2000 + u];
        const float bh1 = b1[2000 + u];
#pragma unroll
        for (int r = 0; r < 8; ++r) {
            const float z   = 1.f / (1.f + __expf(-(az[r] + bz)));
            const float rg_ = 1.f / (1.f + __expf(-(ar[r] + br)));
            const float pre = ah[r] + bh0 + rg_ * bh1;
            const float ex  = __expf(2.f * pre);
            const float hh  = 1.f - 2.f / (ex + 1.f);
            h1h[(ibase + r) * HSTR + u] = (half_t)(msk[r] ? (1.f - z) * hh : 0.f);
        }
    } else {
        const half_t cv = (half_t)((u == 1000) ? 1.f : 0.f);
#pragma unroll
        for (int r = 0; r < 8; ++r)
            h1h[(ibase + r) * HSTR + u] = cv;
    }
}

// ===========================================================================
// kA: P[kb][1024][100] = W-chunk @ E via f16 MFMA 16x16x32.
// Grid dim3(32 mb, 32 kb); block = 4 waves splitting the kb's 32 k-units.
// Wave tile: 32 m-rows (2 MFMA m-tiles sharing B) x 112 n. NB=2 staging.
// LDS cross-wave reduce; wave 0 writes P non-atomically.
// ===========================================================================
__global__ __launch_bounds__(256) void kA(const float* __restrict__ W,
                                          const half_t* __restrict__ ET,
                                          float* __restrict__ P)
{
    __shared__ float red[3][64][57];        // stride 57 (odd): conflict-free
    const int tid   = threadIdx.x;
    const int lane  = tid & 63;
    const int wv    = tid >> 6;
    const int mb    = blockIdx.x;           // 0..31 -> rows mb*32..+31
    const int kb    = blockIdx.y;           // 0..31
    const int row16 = lane & 15;
    const int quad  = lane >> 4;

    const int m0  = mb * 32 + row16;
    const int mc0 = min(m0, UNITS - 1);
    const int mc1 = min(m0 + 16, UNITS - 1);

    const int ub = kb * 32;
    const int ue = min(ub + 32, 1000);
    const int pw = (ue - ub + 3) >> 2;
    const int wb = ub + wv * pw;
    const int we = min(wb + pw, ue);

    floatx4 acc0[7], acc1[7];
#pragma unroll
    for (int t = 0; t < 7; ++t) {
        acc0[t] = (floatx4){0.f, 0.f, 0.f, 0.f};
        acc1[t] = (floatx4){0.f, 0.f, 0.f, 0.f};
    }

    const float* wrow0 = W + (long)mc0 * V1;
    const float* wrow1 = W + (long)mc1 * V1;
    const half_t* bbase[7];
#pragma unroll
    for (int t = 0; t < 7; ++t) {
        const int nc = min(t * 16 + row16, 99);
        bbase[t] = ET + (long)nc * KPAD + quad * 8;
    }

    int un = wb;
    for (; un + 2 <= we; un += 2) {         // NB=2: 8 indep W loads in flight
        float f[2][16];
#pragma unroll
        for (int j = 0; j < 2; ++j) {
            const int k0 = (un + j) * 32 + quad * 8;
            __builtin_memcpy(&f[j][0], wrow0 + k0, 32);
            __builtin_memcpy(&f[j][8], wrow1 + k0, 32);
        }
#pragma unroll
        for (int j = 0; j < 2; ++j) {
            half8 a0, a1;
#pragma unroll
            for (int q = 0; q < 8; ++q) {
                a0[q] = (half_t)f[j][q];
                a1[q] = (half_t)f[j][8 + q];
            }
            const int koff = (un + j) * 32;
#pragma unroll
            for (int t = 0; t < 7; ++t) {
                const half8 b = *(const half8*)(bbase[t] + koff);
                acc0[t] = __builtin_amdgcn_mfma_f32_16x16x32_f16(a0, b, acc0[t], 0, 0, 0);
                acc1[t] = __builtin_amdgcn_mfma_f32_16x16x32_f16(a1, b, acc1[t], 0, 0, 0);
            }
        }
    }
    for (; un < we; ++un) {                 // tail (kb=31: pw=2)
        const int k0 = un * 32 + quad * 8;
        float f0[8], f1[8];
        __builtin_memcpy(f0, wrow0 + k0, 32);
        __builtin_memcpy(f1, wrow1 + k0, 32);
        half8 a0, a1;
#pragma unroll
        for (int q = 0; q < 8; ++q) { a0[q] = (half_t)f0[q]; a1[q] = (half_t)f1[q]; }
#pragma unroll
        for (int t = 0; t < 7; ++t) {
            const half8 b = *(const half8*)(bbase[t] + un * 32);
            acc0[t] = __builtin_amdgcn_mfma_f32_16x16x32_f16(a0, b, acc0[t], 0, 0, 0);
            acc1[t] = __builtin_amdgcn_mfma_f32_16x16x32_f16(a1, b, acc1[t], 0, 0, 0);
        }
    }

    if (wv > 0) {
#pragma unroll
        for (int t = 0; t < 7; ++t)
#pragma unroll
            for (int r = 0; r < 4; ++r) {
                red[wv - 1][lane][t * 4 + r]      = acc0[t][r];
                red[wv - 1][lane][28 + t * 4 + r] = acc1[t][r];
            }
    }
    __syncthreads();
    if (wv == 0) {
        float* Pk = P + (long)kb * (PROWS * 100);
        const int orow0 = mb * 32 + quad * 4;     // C/D: row=(lane>>4)*4+r
#pragma unroll
        for (int t = 0; t < 7; ++t) {
            const int col = t * 16 + row16;       // C/D: col=lane&15
            if (col < 100) {
#pragma unroll
                for (int r = 0; r < 4; ++r) {
                    const int i = t * 4 + r;
                    const float s0 = acc0[t][r] + red[0][lane][i]
                                   + red[1][lane][i] + red[2][lane][i];
                    const float s1 = acc1[t][r] + red[0][lane][28 + i]
                                   + red[1][lane][28 + i] + red[2][lane][28 + i];
                    Pk[(orow0 + r) * 100 + col]      = s0;
                    Pk[(orow0 + 16 + r) * 100 + col] = s1;
                }
            }
        }
    }
}

// ===========================================================================
// kPost: MbT[100][HSTR] f16:
//   kk<1000 : sum_kb P[kb][kk][e]  +  W[kk][32000]*E[32000][e]   (kD fixup)
//   kk==1000: vvec[e];   else 0
// Thread = (kk,e) with e fastest -> coalesced P reads.
// ===========================================================================
__global__ __launch_bounds__(256) void kPost(const float* __restrict__ P,
                                             const float* __restrict__ W,
                                             const float* __restrict__ E,
                                             const float* __restrict__ vvec,
                                             half_t* __restrict__ MbT)
{
    const int idx = blockIdx.x * 256 + threadIdx.x;   // < 1024*100
    const int kk  = idx / 100;
    const int e   = idx - kk * 100;
    float s;
    if (kk < 1000) {
        s = 0.f;
#pragma unroll
        for (int kb = 0; kb < NKB; ++kb)
            s += P[(long)kb * (PROWS * 100) + kk * 100 + e];
        s += W[(long)kk * V1 + 32000] * E[32000 * 100 + e];
    } else if (kk == 1000) {
        s = vvec[e];
    } else {
        s = 0.f;
    }
    MbT[e * HSTR + kk] = (half_t)s;
}

// ===========================================================================
// kC: out[1600][100] = [h1|1] @ [M;v] via f16 MFMA.
// Block = 4 waves splitting K (8 units each), LDS reduce, wave 0 writes.
// ===========================================================================
__global__ __launch_bounds__(256) void kC(const half_t* __restrict__ h1h,
                                          const half_t* __restrict__ MbT,
                                          float* __restrict__ out)
{
    __shared__ float red[3][64][29];
    const int tid   = threadIdx.x;
    const int lane  = tid & 63;
    const int wv    = tid >> 6;
    const int rb    = blockIdx.x;          // 0..99
    const int row16 = lane & 15;
    const int quad  = lane >> 4;

    const half_t* arow = h1h + (long)(rb * 16 + row16) * HSTR + quad * 8;
    const half_t* bbase[7];
#pragma unroll
    for (int t = 0; t < 7; ++t) {
        const int nc = min(t * 16 + row16, 99);
        bbase[t] = MbT + (long)nc * HSTR + quad * 8;
    }

    floatx4 acc[7];
#pragma unroll
    for (int t = 0; t < 7; ++t) acc[t] = (floatx4){0.f, 0.f, 0.f, 0.f};

    const int wb = wv * 8;
#pragma unroll 2
    for (int un = wb; un < wb + 8; ++un) {
        const half8 a = *(const half8*)(arow + un * 32);
#pragma unroll
        for (int t = 0; t < 7; ++t) {
            const half8 b = *(const half8*)(bbase[t] + un * 32);
            acc[t] = __builtin_amdgcn_mfma_f32_16x16x32_f16(a, b, acc[t], 0, 0, 0);
        }
    }

    if (wv > 0) {
#pragma unroll
        for (int t = 0; t < 7; ++t)
#pragma unroll
            for (int r = 0; r < 4; ++r)
                red[wv - 1][lane][t * 4 + r] = acc[t][r];
    }
    __syncthreads();
    if (wv == 0) {
        const int orow0 = rb * 16 + quad * 4;
#pragma unroll
        for (int t = 0; t < 7; ++t) {
            const int col = t * 16 + row16;
            if (col < 100) {
#pragma unroll
                for (int r = 0; r < 4; ++r) {
                    const int i = t * 4 + r;
                    out[(orow0 + r) * 100 + col] = acc[t][r] + red[0][lane][i]
                        + red[1][lane][i] + red[2][lane][i];
                }
            }
        }
    }
}

// ===========================================================================
extern "C" void kernel_launch(void* const* d_in, const int* in_sizes, int n_in,
                              void* d_out, int out_size, void* d_ws, size_t ws_size,
                              hipStream_t stream)
{
    const int*   target     = (const int*)d_in[1];
    const int*   start_tok  = (const int*)d_in[2];
    const float* emb        = (const float*)d_in[3];
    const float* dec_kernel = (const float*)d_in[7];
    const float* dec_bias   = (const float*)d_in[9];
    const float* fc_w       = (const float*)d_in[10];
    const float* fc_b       = (const float*)d_in[11];

    float*  vvec = (float*)d_ws;                         // 128 f32
    half_t* ET   = (half_t*)(vvec + 128);                // 100*KPAD f16 (6.4 MB)
    half_t* h1h  = ET + (size_t)100 * KPAD;              // 1600*HSTR f16 (3.3 MB)
    half_t* MbT  = h1h + (size_t)NROWS * HSTR;           // 100*HSTR f16 (0.2 MB)
    float*  P    = (float*)(MbT + (size_t)100 * HSTR);   // 32*1024*100 f32 (13.1 MB)
    float*  out  = (float*)d_out;

    hipMemsetAsync(vvec, 0, 128 * sizeof(float), stream);

    kPre<<<1557, 256, 0, stream>>>(emb, ET, fc_b, vvec, target, start_tok,
                                   dec_kernel, dec_bias, h1h);
    kA<<<dim3(32, NKB), 256, 0, stream>>>(fc_w, ET, P);
    kPost<<<(PROWS * 100) / 256, 256, 0, stream>>>(P, fc_w, emb, vvec, MbT);
    kC<<<100, 256, 0, stream>>>(h1h, MbT, out);
}